// Round 1
// 2375.389 us; speedup vs baseline: 1.0590x; 1.0590x over previous
//
#include <hip/hip_runtime.h>
#include <stdint.h>

#define B_  128
#define T_  1024
#define H_  512
#define I_  64
#define TB_ 131072   // T_*B_

typedef _Float16 half2_t __attribute__((ext_vector_type(2)));

union U32H2 { uint32_t u; half2_t h; };
union U16H  { uint16_t u; _Float16 h; };

static __device__ __forceinline__ half2_t u2h(uint32_t u){ U32H2 x; x.u=u; return x.h; }
static __device__ __forceinline__ uint32_t h2u(half2_t h){ U32H2 x; x.h=h; return x.u; }

#if defined(__has_builtin)
#if __has_builtin(__builtin_amdgcn_fdot2)
#define HAVE_FDOT2 1
#endif
#endif

static __device__ __forceinline__ float fdot2f(half2_t a, half2_t b, float c){
#ifdef HAVE_FDOT2
    return __builtin_amdgcn_fdot2(a, b, c, false);
#else
    return c + (float)a[0]*(float)b[0] + (float)a[1]*(float)b[1];
#endif
}

// Raw barrier: LDS visibility only (lgkmcnt). Crucially does NOT drain vmcnt,
// so the per-step r-prefetch load and out-store stay in flight across steps.
// (__syncthreads() emits s_waitcnt vmcnt(0) lgkmcnt(0) before s_barrier, which
// serialized ~900cy of HBM latency into every step.)
#define BARRIER_NODRAIN() do {                                        \
    __asm__ __volatile__("s_waitcnt lgkmcnt(0)" ::: "memory");        \
    __builtin_amdgcn_s_barrier();                                     \
    __asm__ __volatile__("" ::: "memory");                            \
} while (0)

// ---------------------------------------------------------------------------
// Kernel A (fused): r[t*128+b][j] = f16( sum_i x[b][t][i]*W_in[j][i] + sigma[j][t*128+b] )
// grid (1024, 8), block 256. Tile: one t (128 b-rows) x 64 j.
// Sigma tile is staged into the As LDS region (reused) after the i-loop.
// ---------------------------------------------------------------------------
__global__ __launch_bounds__(256) void k_wingemm(const float* __restrict__ x,
                                                 const float* __restrict__ Win,
                                                 const float* __restrict__ sigma,
                                                 uint32_t* __restrict__ r2)
{
    __shared__ float As[128*65];   // [b][i], pad 65; reused as Sg[64][130] (8320 floats exactly)
    __shared__ float Ws[64*65];    // [j][i]
    const int t   = blockIdx.x;
    const int j0  = blockIdx.y * 64;
    const int tid = threadIdx.x;

    // stage x[b][t][0:64] -> As[b][:]
#pragma unroll
    for (int k = 0; k < 8; k++){
        int qid = k*256 + tid;           // [0,2048)
        int row = qid >> 4;              // b
        int qq  = qid & 15;
        float4 v = *(const float4*)(x + ((size_t)row*T_ + t)*I_ + qq*4);
        float* d = As + row*65 + qq*4;
        d[0]=v.x; d[1]=v.y; d[2]=v.z; d[3]=v.w;
    }
    // stage W_in[j0+r][0:64] -> Ws[r][:]
#pragma unroll
    for (int k = 0; k < 4; k++){
        int qid = k*256 + tid;           // [0,1024)
        int row = qid >> 4;
        int qq  = qid & 15;
        float4 v = *(const float4*)(Win + (size_t)(j0+row)*I_ + qq*4);
        float* d = Ws + row*65 + qq*4;
        d[0]=v.x; d[1]=v.y; d[2]=v.z; d[3]=v.w;
    }
    __syncthreads();

    const int tj = tid & 15;   // j-pair group (fast-varying lane dim -> coalesced stores)
    const int tb = tid >> 4;   // [0,16)

    float acc[8][2][2];
#pragma unroll
    for (int bb=0; bb<8; bb++)
#pragma unroll
        for (int jj=0; jj<2; jj++){ acc[bb][jj][0]=0.f; acc[bb][jj][1]=0.f; }

#pragma unroll 4
    for (int i = 0; i < 64; i++){
        float a[8];
#pragma unroll
        for (int bb=0; bb<8; bb++) a[bb] = As[(tb + 16*bb)*65 + i];
        float wv[2][2];
#pragma unroll
        for (int jj=0; jj<2; jj++){
            wv[jj][0] = Ws[(2*tj + 32*jj    )*65 + i];
            wv[jj][1] = Ws[(2*tj + 32*jj + 1)*65 + i];
        }
#pragma unroll
        for (int bb=0; bb<8; bb++)
#pragma unroll
            for (int jj=0; jj<2; jj++){
                acc[bb][jj][0] += a[bb]*wv[jj][0];
                acc[bb][jj][1] += a[bb]*wv[jj][1];
            }
    }
    __syncthreads();   // all As reads done; safe to overwrite with sigma tile

    // stage sigma[j0+row][t*128 + 0:128] -> Sg[row][0:128] (pad 130)
    float* Sg = As;
#pragma unroll
    for (int k = 0; k < 8; k++){
        int qid = k*256 + tid;           // [0,2048): 64 rows x 32 float4
        int row = qid >> 5;
        int qq  = qid & 31;
        float4 v = *(const float4*)(sigma + (size_t)(j0+row)*TB_ + (size_t)t*128 + qq*4);
        float* d = Sg + row*130 + qq*4;
        d[0]=v.x; d[1]=v.y; d[2]=v.z; d[3]=v.w;
    }
    __syncthreads();

#pragma unroll
    for (int bb=0; bb<8; bb++){
        int bcol = tb + 16*bb;
        int mi = t*128 + bcol;
#pragma unroll
        for (int jj=0; jj<2; jj++){
            int jA = 2*tj + 32*jj;
            float a0 = acc[bb][jj][0] + Sg[(jA    )*130 + bcol];
            float a1 = acc[bb][jj][1] + Sg[(jA + 1)*130 + bcol];
            half2_t hv; hv[0]=(_Float16)a0; hv[1]=(_Float16)a1;
            r2[(size_t)mi*256 + (j0>>1) + tj + 16*jj] = h2u(hv);
        }
    }
}

// ---------------------------------------------------------------------------
// Kernel B: the recurrence. One workgroup per batch column b. 512 threads.
// Thread t = (wave w, lane l): k-chunk [64w,64w+64); rows {l+64m, m<8}.
// W f16: rows m<6 in 192 VGPR-pairs, rows 6,7 in LDS (rotated, conflict-free b128).
// Per step: 2 raw barriers (lgkmcnt only, no vmcnt drain), 256 v_dot2 / thread,
// LDS partial reduction over 8 waves (par stride-9: conflict-free writes,
// read2-fusable adjacent reads).
// ---------------------------------------------------------------------------
__global__ __launch_bounds__(512, 2) void k_rnn(const float* __restrict__ Wh,
                                                const float* __restrict__ Win,
                                                const float* __restrict__ x,
                                                const float* __restrict__ sigma,
                                                const float* __restrict__ h0,
                                                const uint16_t* __restrict__ r16,
                                                float* __restrict__ out,
                                                int use_r)
{
    extern __shared__ char smem[];
    uint32_t*  WL  = (uint32_t*)smem;                      // [512*64] u32 (f16x2), 128 KB
    float*     par = (float*)(smem + 131072);              // [512*9] floats, 18432 B
    _Float16*  sb  = (_Float16*)(smem + 131072 + 18432);   // [512] sigmoid(h), 1 KB

    const int b = blockIdx.x;
    const int t = threadIdx.x;
    const int w = t >> 6;
    const int l = t & 63;
    const int j = t;
    const int phase = (l & 15) << 2;   // pair rotation, multiple of 4 -> b128 stays contiguous

    // one-time: load W_hidden slice, convert fp32 -> f16 pairs
    half2_t wreg[6][32];
#pragma unroll
    for (int m = 0; m < 8; m++){
        const int row = l + 64*m;
        const float4* wr = (const float4*)(Wh + (size_t)row*H_ + (w << 6));
#pragma unroll
        for (int q = 0; q < 16; q++){
            float4 v = wr[q];
            half2_t a; a[0]=(_Float16)v.x; a[1]=(_Float16)v.y;
            half2_t c; c[0]=(_Float16)v.z; c[1]=(_Float16)v.w;
            int pp = 2*q;
            if (m < 6){
                wreg[m][pp]   = a;
                wreg[m][pp+1] = c;
            } else {
                int base = (m-6)*32;
                WL[t*64 + ((base + pp     + phase) & 63)] = h2u(a);
                WL[t*64 + ((base + pp + 1 + phase) & 63)] = h2u(c);
            }
        }
    }

    float h = h0[(size_t)j*B_ + b];
    const uint32_t* WLt = WL + t*64;
    const uint32_t* sbu = (const uint32_t*)sb;
    float* outp = out + (size_t)b*T_*H_ + j;
    const uint16_t* rp = r16 + (size_t)b*H_ + j;   // element (t*128+b)*512 + j

    for (int ts = 0; ts < T_; ts++){
        // prefetch this step's r (consumed after the dot phase; never drained by barriers)
        uint16_t ru = 0;
        if (use_r) ru = rp[(size_t)ts * 65536];

        // s = sigmoid(h)
        float e = __expf(-h);
        float s = 1.0f / (1.0f + e);
        sb[j] = (_Float16)s;
        BARRIER_NODRAIN();

        float p[8];
#pragma unroll
        for (int m = 0; m < 8; m++) p[m] = 0.f;

#pragma unroll
        for (int c = 0; c < 8; c++){
            uint4 sq = *(const uint4*)(sbu + (w << 5) + (c << 2));   // broadcast: wave-uniform
            half2_t s0=u2h(sq.x), s1=u2h(sq.y), s2=u2h(sq.z), s3=u2h(sq.w);
            uint4 q6 = *(const uint4*)(WLt + ((4*c      + phase) & 63));
            uint4 q7 = *(const uint4*)(WLt + ((32 + 4*c + phase) & 63));
#pragma unroll
            for (int m = 0; m < 6; m++){
                p[m] = fdot2f(wreg[m][4*c+0], s0, p[m]);
                p[m] = fdot2f(wreg[m][4*c+1], s1, p[m]);
                p[m] = fdot2f(wreg[m][4*c+2], s2, p[m]);
                p[m] = fdot2f(wreg[m][4*c+3], s3, p[m]);
            }
            p[6] = fdot2f(u2h(q6.x), s0, p[6]);
            p[6] = fdot2f(u2h(q6.y), s1, p[6]);
            p[6] = fdot2f(u2h(q6.z), s2, p[6]);
            p[6] = fdot2f(u2h(q6.w), s3, p[6]);
            p[7] = fdot2f(u2h(q7.x), s0, p[7]);
            p[7] = fdot2f(u2h(q7.y), s1, p[7]);
            p[7] = fdot2f(u2h(q7.z), s2, p[7]);
            p[7] = fdot2f(u2h(q7.w), s3, p[7]);
        }

        // par[r*9 + w], r = l + 64m: writes conflict-free (9 coprime 32),
        // reads for row j are 8 adjacent floats -> ds_read2_b32 fusable.
#pragma unroll
        for (int m = 0; m < 8; m++) par[(l + (m << 6))*9 + w] = p[m];
        BARRIER_NODRAIN();

        const float* pj = par + j*9;
        float P = ((pj[0] + pj[1]) + (pj[2] + pj[3]))
                + ((pj[4] + pj[5]) + (pj[6] + pj[7]));

        float rv;
        if (use_r){
            U16H cv; cv.u = ru;
            rv = (float)cv.h;
        } else {
            // fallback: w_in inline (W_in from L2 every step) + scattered sigma
            float acc = 0.f;
            const float4* wir = (const float4*)(Win + (size_t)j*I_);
            const float4* xr  = (const float4*)(x + ((size_t)b*T_ + ts)*I_);
#pragma unroll
            for (int q = 0; q < 16; q++){
                float4 a = wir[q]; float4 xx = xr[q];
                acc += a.x*xx.x + a.y*xx.y + a.z*xx.z + a.w*xx.w;
            }
            rv = acc + sigma[((size_t)j << 17) + (ts << 7) + b];
        }

        h = 0.9f*h + 0.1f*(P + rv);
        outp[(size_t)ts * H_] = h;
    }

    // h_last[j][b]
    out[(size_t)B_*T_*H_ + (size_t)j*B_ + b] = h;
}

// ---------------------------------------------------------------------------
extern "C" void kernel_launch(void* const* d_in, const int* in_sizes, int n_in,
                              void* d_out, int out_size, void* d_ws, size_t ws_size,
                              hipStream_t stream)
{
    const float* x     = (const float*)d_in[0];
    const float* Win   = (const float*)d_in[1];
    const float* Wh    = (const float*)d_in[2];
    const float* sigma = (const float*)d_in[3];
    const float* h0    = (const float*)d_in[4];
    float* out = (float*)d_out;

    const size_t r_bytes = (size_t)TB_ * H_ * 2;   // 134,217,728 B (f16 r)
    const int use_r = (ws_size >= r_bytes) ? 1 : 0;

    if (use_r){
        k_wingemm<<<dim3(T_, 8), 256, 0, stream>>>(x, Win, sigma, (uint32_t*)d_ws);
    }

    const int lds_bytes = 131072 + 18432 + 1024;   // 150,528
    (void)hipFuncSetAttribute((const void*)k_rnn,
                              hipFuncAttributeMaxDynamicSharedMemorySize, lds_bytes);
    k_rnn<<<B_, 512, lds_bytes, stream>>>(Wh, Win, x, sigma, h0,
                                          (const uint16_t*)d_ws, out, use_r);
}